// Round 1
// baseline (160.382 us; speedup 1.0000x reference)
//
#include <hip/hip_runtime.h>
#include <hip/hip_bf16.h>

typedef __attribute__((ext_vector_type(8))) short short8;      // 8 bf16 (4 VGPR) MFMA operand
typedef __attribute__((ext_vector_type(4))) float f32x4;       // MFMA accumulator
typedef __attribute__((ext_vector_type(4))) unsigned short u16x4;

#define XLR_STRIDE 520            // elements; 1040 B rows, 16B-aligned, breaks pow2 banks
#define XLR_BYTES  (144 * XLR_STRIDE * 2)   // 149760
#define LDS_BYTES  (XLR_BYTES + 1024 + 1600 + 1600)  // + atts + scores + alphas = 153984

__device__ __forceinline__ unsigned short f2bf(float f) {
    unsigned int u = __float_as_uint(f);
    unsigned int r = (u + 0x7fffu + ((u >> 16) & 1u)) >> 16;   // RNE
    return (unsigned short)r;
}
__device__ __forceinline__ float bf2f(unsigned short h) {
    return __uint_as_float(((unsigned int)h) << 16);
}

// static graph: 16 directed edges + 9 self loops
__device__ const int SRC_E[25] = {0,1,0,3,0,5,0,7,1,2,3,4,5,6,7,8, 0,1,2,3,4,5,6,7,8};
__device__ const int DST_E[25] = {1,0,3,0,5,0,7,0,2,1,4,3,6,5,8,7, 0,1,2,3,4,5,6,7,8};
// incoming-edge lists grouped by destination node
__device__ const int NINC[9]    = {5,3,2,3,2,3,2,3,2};
__device__ const int INC_OFF[9] = {0,5,8,10,13,15,18,20,23};
__device__ const int INC_E[25]  = {1,3,5,7,16, 0,9,17, 8,18, 2,11,19, 10,20, 4,13,21, 12,22, 6,15,23, 14,24};
__device__ const int INC_S[25]  = {1,3,5,7,0,  0,2,1,  1,2,  0,4,3,   3,4,   0,6,5,   5,6,   0,8,7,   7,8};

// WT[n][k] = (n<256 ? W_l[k][n] : W_r[k][n-256]) as bf16  -> B-fragments contiguous
__global__ void convert_w_kernel(const float* __restrict__ Wl,
                                 const float* __restrict__ Wr,
                                 unsigned short* __restrict__ WT) {
    int n = blockIdx.x;      // 0..511
    int k = threadIdx.x;     // 0..255
    float v = (n < 256) ? Wl[k * 256 + n] : Wr[k * 256 + (n - 256)];
    WT[n * 256 + k] = f2bf(v);
}

__global__ __launch_bounds__(512, 2) void gat_fused_kernel(
        const float* __restrict__ x,
        const unsigned short* __restrict__ WT,
        const float* __restrict__ att,
        const float* __restrict__ bias,
        float* __restrict__ out) {
    __shared__ __align__(16) char smem[LDS_BYTES];
    unsigned short* XLR = (unsigned short*)smem;               // phase 2: [144][520] bf16
    float* atts   = (float*)(smem + XLR_BYTES);                // 256 f32
    float* scores = atts + 256;                                // 400 f32
    float* alphas = scores + 400;                              // 400 f32

    const int tid  = threadIdx.x;
    const int lane = tid & 63;
    const int wave = tid >> 6;
    const int blk  = blockIdx.x;

    if (tid < 256) atts[tid] = att[tid];

    // ---- stage X: 16 graphs = 144 rows x 256 cols, fp32 -> bf16, XOR-swizzled ----
    // LDS layout (phase 1, overlaps XLR region): byte = row*512 + ((k*2) ^ ((row&15)<<4))
    const float* xblk = x + (size_t)blk * 36864;
    {
        f32x4 xv[18];
        #pragma unroll
        for (int it = 0; it < 18; ++it)
            xv[it] = *(const f32x4*)(xblk + it * 2048 + tid * 4);
        #pragma unroll
        for (int it = 0; it < 18; ++it) {
            int f   = it * 2048 + tid * 4;
            int row = f >> 8;
            int k   = f & 255;
            int inner = (k * 2) ^ ((row & 15) << 4);
            u16x4 w4 = { f2bf(xv[it][0]), f2bf(xv[it][1]), f2bf(xv[it][2]), f2bf(xv[it][3]) };
            *(u16x4*)(smem + row * 512 + inner) = w4;
        }
    }
    __syncthreads();

    // ---- GEMM: [144 x 256] x [256 x 512] -> acc, wave w owns cols [64w, 64w+64) ----
    const f32x4 ZERO = {0.f, 0.f, 0.f, 0.f};
    f32x4 acc[9][4];
    #pragma unroll
    for (int m = 0; m < 9; ++m)
        #pragma unroll
        for (int n = 0; n < 4; ++n) acc[m][n] = ZERO;

    const int nb = wave * 64;
    // B-frag: lane l -> WT[nb + ntile*16 + (l&15)][kc*32 + (l>>4)*8 + 0..7], 16 B contiguous
    const unsigned short* Wbase = WT + (size_t)((nb + (lane & 15)) * 256 + ((lane >> 4) * 8));
    short8 bnx[4];
    #pragma unroll
    for (int n = 0; n < 4; ++n) bnx[n] = *(const short8*)(Wbase + n * 4096);

    #pragma unroll
    for (int kc = 0; kc < 8; ++kc) {
        short8 bn[4];
        #pragma unroll
        for (int n = 0; n < 4; ++n) bn[n] = bnx[n];
        if (kc < 7) {
            #pragma unroll
            for (int n = 0; n < 4; ++n)
                bnx[n] = *(const short8*)(Wbase + n * 4096 + (kc + 1) * 32);
        }
        // A-frag: lane l -> Xs[mtile*16 + (l&15)][kc*32 + (l>>4)*8 + 0..7] (swizzled)
        short8 am[9];
        const int innerbase = ((kc * 64) + ((lane >> 4) * 16)) ^ ((lane & 15) << 4);
        #pragma unroll
        for (int m = 0; m < 9; ++m) {
            int row = m * 16 + (lane & 15);
            am[m] = *(const short8*)(smem + row * 512 + innerbase);
        }
        #pragma unroll
        for (int m = 0; m < 9; ++m)
            #pragma unroll
            for (int n = 0; n < 4; ++n)
                acc[m][n] = __builtin_amdgcn_mfma_f32_16x16x32_bf16(am[m], bn[n], acc[m][n], 0, 0, 0);
    }
    __syncthreads();   // everyone done reading Xs; region becomes XLR

    // ---- spill acc to LDS as bf16: D[row][col], col=lane&15, row=4*(lane>>4)+r ----
    #pragma unroll
    for (int m = 0; m < 9; ++m) {
        #pragma unroll
        for (int n = 0; n < 4; ++n) {
            int col = nb + n * 16 + (lane & 15);
            #pragma unroll
            for (int r = 0; r < 4; ++r) {
                int row = m * 16 + ((lane >> 4) * 4) + r;
                XLR[row * XLR_STRIDE + col] = f2bf(acc[m][n][r]);
            }
        }
    }
    __syncthreads();

    // ---- per-edge scores: s = sum_d att[d] * lrelu(XL[src][d] + XR[dst][d]) ----
    if (tid < 400) {
        int g = tid / 25, e = tid - g * 25;
        const unsigned short* pl = XLR + (g * 9 + SRC_E[e]) * XLR_STRIDE;        // XL cols 0..255
        const unsigned short* pr = XLR + (g * 9 + DST_E[e]) * XLR_STRIDE + 256;  // XR cols 256..511
        float s = 0.f;
        #pragma unroll 4
        for (int dc = 0; dc < 32; ++dc) {
            short8 a = *(const short8*)(pl + dc * 8);
            short8 b = *(const short8*)(pr + dc * 8);
            f32x4 at0 = *(const f32x4*)(atts + dc * 8);
            f32x4 at1 = *(const f32x4*)(atts + dc * 8 + 4);
            #pragma unroll
            for (int j = 0; j < 8; ++j) {
                float vv = bf2f((unsigned short)a[j]) + bf2f((unsigned short)b[j]);
                vv = vv > 0.f ? vv : 0.2f * vv;
                float aj = (j < 4) ? at0[j] : at1[j - 4];
                s += aj * vv;
            }
        }
        scores[tid] = s;
    }
    __syncthreads();

    // ---- segment softmax over incoming edges of each (graph, node) ----
    if (tid < 144) {
        int g = tid / 9, n = tid - g * 9;
        int off = INC_OFF[n], cnt = NINC[n];
        float mx = -1e30f;
        for (int i = 0; i < cnt; ++i) mx = fmaxf(mx, scores[g * 25 + INC_E[off + i]]);
        float ssum = 0.f;
        for (int i = 0; i < cnt; ++i) ssum += __expf(scores[g * 25 + INC_E[off + i]] - mx);
        float inv = 1.f / ssum;
        for (int i = 0; i < cnt; ++i) {
            int e = INC_E[off + i];
            alphas[g * 25 + e] = __expf(scores[g * 25 + e] - mx) * inv;
        }
    }
    __syncthreads();

    // ---- aggregate: out[row][d] = bias[d] + sum_inc alpha * XL[src][d] ----
    const int d0 = lane * 4;                         // 64 lanes x 4 cols = 256
    f32x4 bv = *(const f32x4*)(bias + d0);
    float* outblk = out + (size_t)blk * 36864;
    for (int p = 0; p < 18; ++p) {
        int row = p * 8 + wave;                      // 18*8 = 144 rows
        int g = row / 9, n = row - g * 9;
        int off = INC_OFF[n], cnt = NINC[n];
        f32x4 v = bv;
        for (int i = 0; i < cnt; ++i) {
            float a = alphas[g * 25 + INC_E[off + i]];
            const unsigned short* pl = XLR + (g * 9 + INC_S[off + i]) * XLR_STRIDE + d0;
            u16x4 u = *(const u16x4*)pl;
            v[0] += a * bf2f(u[0]);
            v[1] += a * bf2f(u[1]);
            v[2] += a * bf2f(u[2]);
            v[3] += a * bf2f(u[3]);
        }
        *(f32x4*)(outblk + row * 256 + d0) = v;
    }
}

extern "C" void kernel_launch(void* const* d_in, const int* in_sizes, int n_in,
                              void* d_out, int out_size, void* d_ws, size_t ws_size,
                              hipStream_t stream) {
    const float* x    = (const float*)d_in[0];
    const float* Wl   = (const float*)d_in[1];
    const float* Wr   = (const float*)d_in[2];
    const float* att  = (const float*)d_in[3];
    const float* bias = (const float*)d_in[4];
    float* out = (float*)d_out;
    unsigned short* WT = (unsigned short*)d_ws;      // 512*256 bf16 = 256 KB

    convert_w_kernel<<<512, 256, 0, stream>>>(Wl, Wr, WT);
    gat_fused_kernel<<<1024, 512, 0, stream>>>(x, WT, att, bias, out);
}

// Round 2
// 137.754 us; speedup vs baseline: 1.1643x; 1.1643x over previous
//
#include <hip/hip_runtime.h>
#include <hip/hip_bf16.h>

typedef __attribute__((ext_vector_type(8))) short short8;      // 8 bf16 MFMA operand
typedef __attribute__((ext_vector_type(4))) float f32x4;
typedef __attribute__((ext_vector_type(4))) unsigned short u16x4;

// LDS: stage [144 rows][512 B] swizzled bf16, then partials + alphas
#define STAGE_BYTES (144 * 512)                    // 73728
#define PART_OFF    STAGE_BYTES                    // [8][25][16] f32 = 12800 B
#define ALPHA_OFF   (PART_OFF + 8 * 25 * 16 * 4)   // 86528
#define LDS_BYTES   (ALPHA_OFF + 25 * 16 * 4)      // 88128

__device__ __forceinline__ unsigned short f2bf(float f) {
    unsigned int u = __float_as_uint(f);
    unsigned int r = (u + 0x7fffu + ((u >> 16) & 1u)) >> 16;   // RNE
    return (unsigned short)r;
}

// static graph tables (compile-time foldable in unrolled loops)
constexpr int C_SRC[25] = {0,1,0,3,0,5,0,7,1,2,3,4,5,6,7,8, 0,1,2,3,4,5,6,7,8};
constexpr int C_DST[25] = {1,0,3,0,5,0,7,0,2,1,4,3,6,5,8,7, 0,1,2,3,4,5,6,7,8};
constexpr int C_NINC[9]  = {5,3,2,3,2,3,2,3,2};
constexpr int C_IOFF[9]  = {0,5,8,10,13,15,18,20,23};
constexpr int C_INCE[25] = {1,3,5,7,16, 0,9,17, 8,18, 2,11,19, 10,20, 4,13,21, 12,22, 6,15,23, 14,24};
constexpr int C_INCS[25] = {1,3,5,7,0,  0,2,1,  1,2,  0,4,3,  3,4,  0,6,5,  5,6,  0,8,7,  7,8};
// runtime-indexed copies (softmax phase) live in global const memory, not scratch
__device__ const int D_NINC[9]  = {5,3,2,3,2,3,2,3,2};
__device__ const int D_IOFF[9]  = {0,5,8,10,13,15,18,20,23};
__device__ const int D_INCE[25] = {1,3,5,7,16, 0,9,17, 8,18, 2,11,19, 10,20, 4,13,21, 12,22, 6,15,23, 14,24};

// WT[n][k] = (n<256 ? W_l[k][n] : W_r[k][n-256]) as bf16 (B-fragments contiguous)
__global__ void convert_w_kernel(const float* __restrict__ Wl,
                                 const float* __restrict__ Wr,
                                 unsigned short* __restrict__ WT) {
    int n = blockIdx.x;      // 0..511
    int k = threadIdx.x;     // 0..255
    float v = (n < 256) ? Wl[k * 256 + n] : Wr[k * 256 + (n - 256)];
    WT[n * 256 + k] = f2bf(v);
}

__global__ __launch_bounds__(512, 2) void gat_fused_kernel(
        const float* __restrict__ x,
        const unsigned short* __restrict__ WT,
        const float* __restrict__ att,
        const float* __restrict__ bias,
        float* __restrict__ out) {
    __shared__ __align__(16) char smem[LDS_BYTES];
    float* partials = (float*)(smem + PART_OFF);   // [wave][edge][graph]
    float* alphas   = (float*)(smem + ALPHA_OFF);  // [edge][graph]

    const int tid  = threadIdx.x;
    const int lane = tid & 63;
    const int w    = tid >> 6;        // 8 waves; wave owns XL cols [32w,32w+32) + XR same
    const int gl   = lane >> 4;       // row group: graphs 4*gl..4*gl+3
    const int li   = lane & 15;       // column-within-tile
    const int blk  = blockIdx.x;

    // per-lane att/bias scalars for this wave's two 16-col tiles
    const int c0 = 32 * w + li, c1 = c0 + 16;
    const float attc0 = att[c0], attc1 = att[c1];
    const float bc0   = bias[c0], bc1 = bias[c1];

    // ---- phase 1: stage x -> LDS bf16, node-major rows (row = node*16 + g), swizzled ----
    const float* xblk = x + (size_t)blk * 36864;
    {
        f32x4 xv[18];
        #pragma unroll
        for (int it = 0; it < 18; ++it)
            xv[it] = *(const f32x4*)(xblk + it * 2048 + tid * 4);
        #pragma unroll
        for (int it = 0; it < 18; ++it) {
            int f    = it * 2048 + tid * 4;
            int gr   = f >> 8;              // g*9 + node
            int c    = f & 255;
            int g    = gr / 9;
            int node = gr - g * 9;
            int srow = node * 16 + g;       // srow & 15 == g
            u16x4 pk = { f2bf(xv[it][0]), f2bf(xv[it][1]), f2bf(xv[it][2]), f2bf(xv[it][3]) };
            *(u16x4*)(smem + srow * 512 + ((2 * c) ^ (g << 4))) = pk;
        }
    }
    __syncthreads();

    // ---- phase 2: GEMM -> registers. aL = x@W_l slice, aR = x@W_r slice ----
    const f32x4 ZERO = {0.f, 0.f, 0.f, 0.f};
    f32x4 aL[9][2], aR[9][2];
    #pragma unroll
    for (int m = 0; m < 9; ++m) {
        aL[m][0] = ZERO; aL[m][1] = ZERO; aR[m][0] = ZERO; aR[m][1] = ZERO;
    }
    const unsigned short* WL0 = WT + (size_t)((32 * w + li) * 256 + gl * 8);
    const unsigned short* WL1 = WL0 + 16 * 256;
    const unsigned short* WR0 = WL0 + 256 * 256;
    const unsigned short* WR1 = WR0 + 16 * 256;

    #pragma unroll
    for (int kc = 0; kc < 8; ++kc) {
        short8 bl0 = *(const short8*)(WL0 + kc * 32);
        short8 bl1 = *(const short8*)(WL1 + kc * 32);
        short8 br0 = *(const short8*)(WR0 + kc * 32);
        short8 br1 = *(const short8*)(WR1 + kc * 32);
        const int inner = ((kc * 64) + (gl * 16)) ^ (li << 4);
        short8 am[9];
        #pragma unroll
        for (int m = 0; m < 9; ++m)
            am[m] = *(const short8*)(smem + (m * 16 + li) * 512 + inner);
        #pragma unroll
        for (int m = 0; m < 9; ++m) {
            aL[m][0] = __builtin_amdgcn_mfma_f32_16x16x32_bf16(am[m], bl0, aL[m][0], 0, 0, 0);
            aL[m][1] = __builtin_amdgcn_mfma_f32_16x16x32_bf16(am[m], bl1, aL[m][1], 0, 0, 0);
            aR[m][0] = __builtin_amdgcn_mfma_f32_16x16x32_bf16(am[m], br0, aR[m][0], 0, 0, 0);
            aR[m][1] = __builtin_amdgcn_mfma_f32_16x16x32_bf16(am[m], br1, aR[m][1], 0, 0, 0);
        }
    }
    // D-frag: col = li (within tile), row = 4*gl + r = graph. No barrier needed here:
    // stage region is not reused; partials region is disjoint.

    // ---- phase 3: per-edge scores, fully in registers + 16-lane butterfly ----
    #pragma unroll
    for (int e = 0; e < 25; ++e) {
        const int s = C_SRC[e], d = C_DST[e];
        float p0 = 0.f, p1 = 0.f, p2 = 0.f, p3 = 0.f;
        #pragma unroll
        for (int nt = 0; nt < 2; ++nt) {
            const float ac = nt ? attc1 : attc0;
            #pragma unroll
            for (int r = 0; r < 4; ++r) {
                float v  = aL[s][nt][r] + aR[d][nt][r];
                float lr = fmaxf(v, 0.2f * v);          // LeakyReLU(0.2)
                float t  = ac * lr;
                if (r == 0) p0 += t; else if (r == 1) p1 += t;
                else if (r == 2) p2 += t; else p3 += t;
            }
        }
        #pragma unroll
        for (int m = 1; m < 16; m <<= 1) {              // sum over the 16 cols of this wave
            p0 += __shfl_xor(p0, m);
            p1 += __shfl_xor(p1, m);
            p2 += __shfl_xor(p2, m);
            p3 += __shfl_xor(p3, m);
        }
        if (li == 0) {
            f32x4 pk = {p0, p1, p2, p3};
            *(f32x4*)(partials + (w * 25 + e) * 16 + 4 * gl) = pk;
        }
    }
    __syncthreads();

    // ---- phase 4: segment softmax, one thread per (node, graph) ----
    if (tid < 144) {
        int n = tid >> 4, g = tid & 15;
        int off = D_IOFF[n], cnt = D_NINC[n];
        float mx = -1e30f;
        for (int i = 0; i < cnt; ++i) {
            int e = D_INCE[off + i];
            float s = 0.f;
            #pragma unroll
            for (int ww = 0; ww < 8; ++ww) s += partials[(ww * 25 + e) * 16 + g];
            alphas[e * 16 + g] = s;                     // scratch: raw score
            mx = fmaxf(mx, s);
        }
        float ssum = 0.f;
        for (int i = 0; i < cnt; ++i)
            ssum += __expf(alphas[D_INCE[off + i] * 16 + g] - mx);
        float inv = 1.f / ssum;
        for (int i = 0; i < cnt; ++i) {
            int e = D_INCE[off + i];
            alphas[e * 16 + g] = __expf(alphas[e * 16 + g] - mx) * inv;
        }
    }
    __syncthreads();

    // ---- phase 5: aggregate in registers (alpha is tile-diagonal in node-major order) ----
    #pragma unroll
    for (int n = 0; n < 9; ++n) {
        f32x4 o0 = {bc0, bc0, bc0, bc0};
        f32x4 o1 = {bc1, bc1, bc1, bc1};
        #pragma unroll
        for (int i = 0; i < C_NINC[n]; ++i) {
            const int e  = C_INCE[C_IOFF[n] + i];
            const int sn = C_INCS[C_IOFF[n] + i];
            f32x4 al = *(const f32x4*)(alphas + e * 16 + 4 * gl);   // alpha for graphs 4gl..4gl+3
            #pragma unroll
            for (int r = 0; r < 4; ++r) {
                o0[r] += al[r] * aL[sn][0][r];
                o1[r] += al[r] * aL[sn][1][r];
            }
        }
        #pragma unroll
        for (int r = 0; r < 4; ++r) {
            size_t row = (size_t)(blk * 16 + 4 * gl + r) * 9 + n;
            out[row * 256 + c0] = o0[r];
            out[row * 256 + c1] = o1[r];
        }
    }
}

extern "C" void kernel_launch(void* const* d_in, const int* in_sizes, int n_in,
                              void* d_out, int out_size, void* d_ws, size_t ws_size,
                              hipStream_t stream) {
    const float* x    = (const float*)d_in[0];
    const float* Wl   = (const float*)d_in[1];
    const float* Wr   = (const float*)d_in[2];
    const float* att  = (const float*)d_in[3];
    const float* bias = (const float*)d_in[4];
    float* out = (float*)d_out;
    unsigned short* WT = (unsigned short*)d_ws;      // 512*256 bf16 = 256 KB

    convert_w_kernel<<<512, 256, 0, stream>>>(Wl, Wr, WT);
    gat_fused_kernel<<<1024, 512, 0, stream>>>(x, WT, att, bias, out);
}